// Round 15
// baseline (365.194 us; speedup 1.0000x reference)
//
#include <hip/hip_runtime.h>
#include <cstdint>
#include <cstddef>

#define CH 128

typedef __attribute__((ext_vector_type(8))) short bf16x8;
typedef __attribute__((ext_vector_type(4))) float f32x4;

__device__ __forceinline__ unsigned short f2bf(float x){
    unsigned int u = __float_as_uint(x);
    u = (u + 0x7FFFu + ((u >> 16) & 1u)) >> 16;   // RNE
    return (unsigned short)u;
}
__device__ __forceinline__ float bf2f(unsigned short b){
    return __uint_as_float(((unsigned int)b) << 16);
}
// HW packed f32x2 -> bf16x2 (RNE), one VALU instr (gfx950 v_cvt_pk_bf16_f32)
__device__ __forceinline__ unsigned int cvtpk_bf16(float lo, float hi){
    unsigned int r;
    asm("v_cvt_pk_bf16_f32 %0, %1, %2" : "=v"(r) : "v"(lo), "v"(hi));
    return r;
}
__device__ __forceinline__ unsigned int pairadd_bf(unsigned int a, unsigned int b){
    float lo = bf2f((unsigned short)(a & 0xffff)) + bf2f((unsigned short)(b & 0xffff));
    float hi = bf2f((unsigned short)(a >> 16))    + bf2f((unsigned short)(b >> 16));
    return cvtpk_bf16(lo, hi);
}

// ---------------------------------------------------------------------------
// k0: transpose+convert weights to bf16 wT[mat][n][k]; zero sums[256*256].
// ---------------------------------------------------------------------------
__global__ __launch_bounds__(256) void k0_prep(
        const float* __restrict__ w_self, const float* __restrict__ w_h,
        const float* __restrict__ w_t, unsigned short* __restrict__ wT,
        float* __restrict__ sums){
    int t = blockIdx.x * 256 + threadIdx.x;
    if (t < 256*256) sums[t] = 0.f;
    if (t < 3*CH*CH){
        int mat = t / (CH*CH);
        int r = t - mat*(CH*CH);
        int k = r >> 7, n = r & 127;
        const float* w = (mat == 0) ? w_self : ((mat == 1) ? w_h : w_t);
        wT[mat*CH*CH + n*CH + k] = f2bf(w[k*CH + n]);
    }
}

// ---------------------------------------------------------------------------
// k1: H = x @ w_h, T = x @ w_t  (bf16 out, f32 MFMA accumulate). Proven R0-R14.
// ---------------------------------------------------------------------------
__global__ __launch_bounds__(512) void k1_ht(
        const float* __restrict__ x, const unsigned short* __restrict__ wT,
        unsigned short* __restrict__ H, unsigned short* __restrict__ T, int N){
    __shared__ __align__(16) unsigned char smem[98304];
    const int tid = threadIdx.x;
    const int m0 = blockIdx.x * 128;
    #pragma unroll
    for (int i = 0; i < 8; ++i){
        int g = tid + i*512;
        int row = g >> 5, col4 = (g & 31) * 4;
        int rg = m0 + row; rg = rg < N ? rg : N-1;
        float4 v = *(const float4*)(x + (size_t)rg*CH + col4);
        unsigned int lo = cvtpk_bf16(v.x, v.y);
        unsigned int hi = cvtpk_bf16(v.z, v.w);
        unsigned int b = ((unsigned int)(row*256 + col4*2)) ^ ((unsigned int)(row & 7) << 4);
        *(uint2*)(smem + b) = make_uint2(lo, hi);
    }
    #pragma unroll
    for (int m = 0; m < 2; ++m){
        const unsigned short* src = wT + (m+1)*CH*CH;
        unsigned char* dst = smem + 32768 + m*32768;
        #pragma unroll
        for (int i = 0; i < 4; ++i){
            int g = tid + i*512;
            int n = g >> 4, k8 = (g & 15) * 8;
            uint4 v = *(const uint4*)(src + n*CH + k8);
            unsigned int b = ((unsigned int)(n*256 + k8*2)) ^ ((unsigned int)(n & 7) << 4);
            *(uint4*)(dst + b) = v;
        }
    }
    __syncthreads();
    const int lane = tid & 63, wv = tid >> 6;
    const int lr = lane & 15, lg = lane >> 4;
    f32x4 accH[8], accT[8];
    #pragma unroll
    for (int n = 0; n < 8; ++n){ accH[n] = (f32x4){0.f,0.f,0.f,0.f}; accT[n] = (f32x4){0.f,0.f,0.f,0.f}; }
    #pragma unroll
    for (int kk = 0; kk < 4; ++kk){
        int arow = wv*16 + lr;
        unsigned int ab = ((unsigned int)(arow*256 + kk*64 + lg*16)) ^ ((unsigned int)(arow & 7) << 4);
        bf16x8 a = *(const bf16x8*)(smem + ab);
        #pragma unroll
        for (int n = 0; n < 8; ++n){
            int cc = n*16 + lr;
            unsigned int bb = ((unsigned int)(cc*256 + kk*64 + lg*16)) ^ ((unsigned int)(cc & 7) << 4);
            bf16x8 bh = *(const bf16x8*)(smem + 32768 + bb);
            bf16x8 bt = *(const bf16x8*)(smem + 65536 + bb);
            accH[n] = __builtin_amdgcn_mfma_f32_16x16x32_bf16(a, bh, accH[n], 0, 0, 0);
            accT[n] = __builtin_amdgcn_mfma_f32_16x16x32_bf16(a, bt, accT[n], 0, 0, 0);
        }
    }
    #pragma unroll
    for (int n = 0; n < 8; ++n){
        int cc = n*16 + lr;
        #pragma unroll
        for (int j = 0; j < 4; ++j){
            int mr = m0 + wv*16 + lg*4 + j;
            if (mr < N){
                H[(size_t)mr*CH + cc] = f2bf(accH[n][j]);
                T[(size_t)mr*CH + cc] = f2bf(accT[n][j]);
            }
        }
    }
}

// ---------------------------------------------------------------------------
// k2v (R13 structure, VALU-trimmed): u=h+t pre-add, frag-linear VB4 store,
//   v_cvt_pk_bf16_f32 for all hot f32->bf16 packing (A-stage, pairadd, v).
// ---------------------------------------------------------------------------
__global__ __launch_bounds__(512, 2) void k2v(
        const float* __restrict__ ea, const int* __restrict__ eidx,
        const unsigned short* __restrict__ wT,
        const unsigned short* __restrict__ Hm, const unsigned short* __restrict__ Tm,
        uint4* __restrict__ VB4, float* __restrict__ sums, int E){
    __shared__ __align__(16) unsigned char smem[66560];   // A 32K | B->U 32K | red 1K
    float* red = (float*)(smem + 65536);
    const int tid = threadIdx.x;
    const int e0 = blockIdx.x * 128;
    if (tid < 256) red[tid] = 0.f;

    // ---- phase 0: edge-index loads ----
    int ri4[4], ci4[4];
    #pragma unroll
    for (int i = 0; i < 4; ++i){
        int r = (tid + i*512) >> 4;
        ri4[i] = eidx[e0 + r];
        ci4[i] = eidx[E + e0 + r];
    }
    __builtin_amdgcn_sched_barrier(0);
    // ---- phase 1: weight tile loads (L2-hot) ----
    uint4 wv4[4];
    #pragma unroll
    for (int i = 0; i < 4; ++i){
        int g = tid + i*512;
        int n = g >> 4, k8 = (g & 15)*8;
        wv4[i] = *(const uint4*)(wT + n*CH + k8);
    }
    __builtin_amdgcn_sched_barrier(0);
    // ---- phase 2: streaming ea loads ----
    float4 eav[8];
    #pragma unroll
    for (int i = 0; i < 8; ++i){
        int g = tid + i*512;
        int row = g >> 5, col4 = (g & 31)*4;
        eav[i] = *(const float4*)(ea + (size_t)(e0+row)*CH + col4);
    }
    __builtin_amdgcn_sched_barrier(0);
    // ---- phase 3: issue H/T gathers (vmcnt waits only eidx) ----
    uint4 hv[4], tv[4];
    #pragma unroll
    for (int i = 0; i < 4; ++i){
        int c = (tid + i*512) & 15;
        hv[i] = *(const uint4*)(Hm + (size_t)ri4[i]*CH + c*8);
        tv[i] = *(const uint4*)(Tm + (size_t)ci4[i]*CH + c*8);
    }
    __builtin_amdgcn_sched_barrier(0);
    // ---- phase 4: wv4 -> B LDS (wv4 dies; eav+gathers stay in flight) ----
    #pragma unroll
    for (int i = 0; i < 4; ++i){
        int g = tid + i*512;
        int n = g >> 4, k8 = (g & 15)*8;
        unsigned int b = ((unsigned int)(n*256 + k8*2)) ^ ((unsigned int)(n & 7) << 4);
        *(uint4*)(smem + 32768 + b) = wv4[i];
    }
    __builtin_amdgcn_sched_barrier(0);
    // ---- phase 5: stage ea -> bf16 A LDS (gathers stay out) ----
    #pragma unroll
    for (int i = 0; i < 8; ++i){
        int g = tid + i*512;
        int row = g >> 5, col4 = (g & 31)*4;
        float4 v = eav[i];
        unsigned int lo = cvtpk_bf16(v.x, v.y);
        unsigned int hi = cvtpk_bf16(v.z, v.w);
        unsigned int b = ((unsigned int)(row*256 + col4*2)) ^ ((unsigned int)(row & 7) << 4);
        *(uint2*)(smem + b) = make_uint2(lo, hi);
    }
    // B1: LDS-only barrier (gathers NOT drained)
    asm volatile("s_waitcnt lgkmcnt(0)\n\ts_barrier" ::: "memory");

    const int lane = tid & 63, wv = tid >> 6;
    const int lr = lane & 15, lg = lane >> 4;
    f32x4 acc[8];
    #pragma unroll
    for (int n = 0; n < 8; ++n) acc[n] = (f32x4){0.f,0.f,0.f,0.f};
    #pragma unroll
    for (int kk = 0; kk < 4; ++kk){
        int arow = wv*16 + lr;
        unsigned int ab = ((unsigned int)(arow*256 + kk*64 + lg*16)) ^ ((unsigned int)(arow & 7) << 4);
        bf16x8 a = *(const bf16x8*)(smem + ab);
        #pragma unroll
        for (int n = 0; n < 8; ++n){
            int cc = n*16 + lr;
            unsigned int bb = ((unsigned int)(cc*256 + kk*64 + lg*16)) ^ ((unsigned int)(cc & 7) << 4);
            bf16x8 bw = *(const bf16x8*)(smem + 32768 + bb);
            acc[n] = __builtin_amdgcn_mfma_f32_16x16x32_bf16(a, bw, acc[n], 0, 0, 0);
        }
    }
    // ---- residual: read staged ea (bf16) ----
    float res[32];
    #pragma unroll
    for (int n = 0; n < 8; ++n){
        int cc = n*16 + lr;
        #pragma unroll
        for (int j = 0; j < 4; ++j){
            int ml = wv*16 + lg*4 + j;
            unsigned int b = ((unsigned int)(ml*256 + cc*2)) ^ ((unsigned int)(ml & 7) << 4);
            res[n*4 + j] = bf2f(*(const unsigned short*)(smem + b));
        }
    }
    asm volatile("s_waitcnt lgkmcnt(0)\n\ts_barrier" ::: "memory");   // B2: B region free
    // ---- redistribute: u = h+t -> u-tile (B region), 4 b128 writes ----
    #pragma unroll
    for (int i = 0; i < 4; ++i){
        int g = tid + i*512;
        int r = g >> 4, c = g & 15;
        uint4 u4;
        u4.x = pairadd_bf(hv[i].x, tv[i].x);
        u4.y = pairadd_bf(hv[i].y, tv[i].y);
        u4.z = pairadd_bf(hv[i].z, tv[i].z);
        u4.w = pairadd_bf(hv[i].w, tv[i].w);
        unsigned int b = ((unsigned int)(r*256 + c*16)) ^ ((unsigned int)((r >> 2) & 3) << 5);
        *(uint4*)(smem + 32768 + b) = u4;
    }
    asm volatile("s_waitcnt lgkmcnt(0)\n\ts_barrier" ::: "memory");   // B3: u visible
    // ---- epilogue: v = o0*(1+0.5u) + res; stats; frag-linear VB4 store ----
    #pragma unroll
    for (int n2 = 0; n2 < 4; ++n2){
        unsigned int ow[4];
        #pragma unroll
        for (int h = 0; h < 2; ++h){
            int nn = n2*2 + h;
            int cc = nn*16 + lr;
            float s = 0.f, ss = 0.f;
            float vj[4];
            #pragma unroll
            for (int j = 0; j < 4; ++j){
                int ml = wv*16 + lg*4 + j;
                unsigned int b = ((unsigned int)(ml*256 + cc*2)) ^ ((unsigned int)((ml >> 2) & 3) << 5);
                float u = bf2f(*(const unsigned short*)(smem + 32768 + b));
                float o0 = acc[nn][j];
                float v = fmaf(o0, 0.5f*u, o0) + res[nn*4 + j];
                s += v; ss += v*v;
                vj[j] = v;
            }
            ow[h*2]   = cvtpk_bf16(vj[0], vj[1]);
            ow[h*2+1] = cvtpk_bf16(vj[2], vj[3]);
            s  += __shfl_xor(s, 16);  s  += __shfl_xor(s, 32);
            ss += __shfl_xor(ss, 16); ss += __shfl_xor(ss, 32);
            if (lane < 16){
                atomicAdd(&red[cc], s);
                atomicAdd(&red[CH + cc], ss);
            }
        }
        uint4 o; o.x = ow[0]; o.y = ow[1]; o.z = ow[2]; o.w = ow[3];
        VB4[((size_t)(blockIdx.x*8 + wv)*4 + n2)*64 + lane] = o;   // coalesced 1KB/wave
    }
    asm volatile("s_waitcnt lgkmcnt(0)\n\ts_barrier" ::: "memory");   // red complete
    if (tid < 256) atomicAdd(&sums[(blockIdx.x & 255)*256 + tid], red[tid]);
}

// ---------------------------------------------------------------------------
// k3: reduce 256 slots -> per-channel scale/shift (sb)
// ---------------------------------------------------------------------------
__global__ __launch_bounds__(128) void k3_stats(
        const float* __restrict__ sums, const float* __restrict__ gamma,
        const float* __restrict__ beta, float* __restrict__ sb, float invE){
    int c = threadIdx.x;
    float s = 0.f, ss = 0.f;
    for (int i = 0; i < 256; ++i){ s += sums[i*256 + c]; ss += sums[i*256 + CH + c]; }
    float mean = s * invE;
    float var = ss * invE - mean*mean;     // biased variance (matches reference)
    float inv = rsqrtf(var + 1e-5f);
    float sc = gamma[c] * inv;
    sb[c] = sc;
    sb[CH + c] = beta[c] - mean * sc;
}

// ---------------------------------------------------------------------------
// kE1: decode fragment-linear VB4 (BM=128 tiles), BN+ReLU, 64B-segment stores.
//   uint4 i: lane=i&63, n2=(i>>6)&3, wv=(i>>8)&7, blk=i>>11.
//   cols n2*32+lr (x,y) / +16 (z,w); rows blk*128 + wv*16 + lg*4 + j.
// ---------------------------------------------------------------------------
__global__ __launch_bounds__(256) void kE1(
        const uint4* __restrict__ VB4, const float* __restrict__ sb,
        float* __restrict__ out, int nt){
    int i = blockIdx.x * 256 + threadIdx.x;
    int stride = gridDim.x * 256;
    for (; i < nt; i += stride){
        uint4 v = VB4[i];
        int lane = i & 63, n2 = (i >> 6) & 3, wv = (i >> 8) & 7, blk = i >> 11;
        int lr = lane & 15, lg = lane >> 4;
        int colA = n2*32 + lr, colB = colA + 16;
        float scA = sb[colA], shA = sb[CH + colA];
        float scB = sb[colB], shB = sb[CH + colB];
        float* o = out + ((size_t)blk*128 + wv*16 + lg*4)*CH;
        o[0*CH + colA] = fmaxf(fmaf(bf2f((unsigned short)(v.x & 0xffff)), scA, shA), 0.f);
        o[1*CH + colA] = fmaxf(fmaf(bf2f((unsigned short)(v.x >> 16)),    scA, shA), 0.f);
        o[2*CH + colA] = fmaxf(fmaf(bf2f((unsigned short)(v.y & 0xffff)), scA, shA), 0.f);
        o[3*CH + colA] = fmaxf(fmaf(bf2f((unsigned short)(v.y >> 16)),    scA, shA), 0.f);
        o[0*CH + colB] = fmaxf(fmaf(bf2f((unsigned short)(v.z & 0xffff)), scB, shB), 0.f);
        o[1*CH + colB] = fmaxf(fmaf(bf2f((unsigned short)(v.z >> 16)),    scB, shB), 0.f);
        o[2*CH + colB] = fmaxf(fmaf(bf2f((unsigned short)(v.w & 0xffff)), scB, shB), 0.f);
        o[3*CH + colB] = fmaxf(fmaf(bf2f((unsigned short)(v.w >> 16)),    scB, shB), 0.f);
    }
}

extern "C" void kernel_launch(void* const* d_in, const int* in_sizes, int n_in,
                              void* d_out, int out_size, void* d_ws, size_t ws_size,
                              hipStream_t stream) {
    const float* x      = (const float*)d_in[0];
    const int*   eidx   = (const int*)d_in[1];
    const float* ea     = (const float*)d_in[2];
    const float* w_self = (const float*)d_in[4];
    const float* w_h    = (const float*)d_in[5];
    const float* w_t    = (const float*)d_in[6];
    const float* gamma  = (const float*)d_in[7];
    const float* beta   = (const float*)d_in[8];
    float* out = (float*)d_out;

    const int N = in_sizes[0] / CH;     // 40000
    const int E = in_sizes[3];          // 640000

    // workspace carve-up (~185 MB total — proven to fit since R5):
    float* sums = (float*)d_ws;                          // 256*256 f32
    float* sb   = sums + 256*256;                        // 256 f32
    unsigned short* wT = (unsigned short*)(sb + 256);    // 3*128*128 bf16
    unsigned short* H  = wT + 3*CH*CH;                   // N*128 bf16
    unsigned short* T  = H + (size_t)N*CH;               // N*128 bf16
    uint4* VB4 = (uint4*)(T + (size_t)N*CH);             // E*128 bf16 (frag-linear)

    k0_prep<<<256, 256, 0, stream>>>(w_self, w_h, w_t, wT, sums);
    k1_ht  <<<(N + 127)/128, 512, 0, stream>>>(x, wT, H, T, N);
    k2v    <<<E/128, 512, 0, stream>>>(ea, eidx, wT, H, T, VB4, sums, E);
    k3_stats<<<1, 128, 0, stream>>>(sums, gamma, beta, sb, 1.0f/(float)E);
    kE1    <<<2048, 256, 0, stream>>>(VB4, sb, out, E*CH/8);
}

// Round 16
// 300.546 us; speedup vs baseline: 1.2151x; 1.2151x over previous
//
#include <hip/hip_runtime.h>
#include <cstdint>
#include <cstddef>

#define CH 128

typedef __attribute__((ext_vector_type(8))) short bf16x8;
typedef __attribute__((ext_vector_type(4))) float f32x4;

__device__ __forceinline__ unsigned short f2bf(float x){
    unsigned int u = __float_as_uint(x);
    u = (u + 0x7FFFu + ((u >> 16) & 1u)) >> 16;   // RNE
    return (unsigned short)u;
}
__device__ __forceinline__ float bf2f(unsigned short b){
    return __uint_as_float(((unsigned int)b) << 16);
}
__device__ __forceinline__ unsigned int pairadd_bf(unsigned int a, unsigned int b){
    float lo = bf2f((unsigned short)(a & 0xffff)) + bf2f((unsigned short)(b & 0xffff));
    float hi = bf2f((unsigned short)(a >> 16))    + bf2f((unsigned short)(b >> 16));
    return (unsigned int)f2bf(lo) | ((unsigned int)f2bf(hi) << 16);
}

// ---------------------------------------------------------------------------
// k0: transpose+convert weights to bf16 wT[mat][n][k]; zero sums[256*256].
// ---------------------------------------------------------------------------
__global__ __launch_bounds__(256) void k0_prep(
        const float* __restrict__ w_self, const float* __restrict__ w_h,
        const float* __restrict__ w_t, unsigned short* __restrict__ wT,
        float* __restrict__ sums){
    int t = blockIdx.x * 256 + threadIdx.x;
    if (t < 256*256) sums[t] = 0.f;
    if (t < 3*CH*CH){
        int mat = t / (CH*CH);
        int r = t - mat*(CH*CH);
        int k = r >> 7, n = r & 127;
        const float* w = (mat == 0) ? w_self : ((mat == 1) ? w_h : w_t);
        wT[mat*CH*CH + n*CH + k] = f2bf(w[k*CH + n]);
    }
}

// ---------------------------------------------------------------------------
// k1: H = x @ w_h, T = x @ w_t  (bf16 out, f32 MFMA accumulate). Proven R0-R15.
// ---------------------------------------------------------------------------
__global__ __launch_bounds__(512) void k1_ht(
        const float* __restrict__ x, const unsigned short* __restrict__ wT,
        unsigned short* __restrict__ H, unsigned short* __restrict__ T, int N){
    __shared__ __align__(16) unsigned char smem[98304];
    const int tid = threadIdx.x;
    const int m0 = blockIdx.x * 128;
    #pragma unroll
    for (int i = 0; i < 8; ++i){
        int g = tid + i*512;
        int row = g >> 5, col4 = (g & 31) * 4;
        int rg = m0 + row; rg = rg < N ? rg : N-1;
        float4 v = *(const float4*)(x + (size_t)rg*CH + col4);
        unsigned int lo = (unsigned int)f2bf(v.x) | ((unsigned int)f2bf(v.y) << 16);
        unsigned int hi = (unsigned int)f2bf(v.z) | ((unsigned int)f2bf(v.w) << 16);
        unsigned int b = ((unsigned int)(row*256 + col4*2)) ^ ((unsigned int)(row & 7) << 4);
        *(uint2*)(smem + b) = make_uint2(lo, hi);
    }
    #pragma unroll
    for (int m = 0; m < 2; ++m){
        const unsigned short* src = wT + (m+1)*CH*CH;
        unsigned char* dst = smem + 32768 + m*32768;
        #pragma unroll
        for (int i = 0; i < 4; ++i){
            int g = tid + i*512;
            int n = g >> 4, k8 = (g & 15) * 8;
            uint4 v = *(const uint4*)(src + n*CH + k8);
            unsigned int b = ((unsigned int)(n*256 + k8*2)) ^ ((unsigned int)(n & 7) << 4);
            *(uint4*)(dst + b) = v;
        }
    }
    __syncthreads();
    const int lane = tid & 63, wv = tid >> 6;
    const int lr = lane & 15, lg = lane >> 4;
    f32x4 accH[8], accT[8];
    #pragma unroll
    for (int n = 0; n < 8; ++n){ accH[n] = (f32x4){0.f,0.f,0.f,0.f}; accT[n] = (f32x4){0.f,0.f,0.f,0.f}; }
    #pragma unroll
    for (int kk = 0; kk < 4; ++kk){
        int arow = wv*16 + lr;
        unsigned int ab = ((unsigned int)(arow*256 + kk*64 + lg*16)) ^ ((unsigned int)(arow & 7) << 4);
        bf16x8 a = *(const bf16x8*)(smem + ab);
        #pragma unroll
        for (int n = 0; n < 8; ++n){
            int cc = n*16 + lr;
            unsigned int bb = ((unsigned int)(cc*256 + kk*64 + lg*16)) ^ ((unsigned int)(cc & 7) << 4);
            bf16x8 bh = *(const bf16x8*)(smem + 32768 + bb);
            bf16x8 bt = *(const bf16x8*)(smem + 65536 + bb);
            accH[n] = __builtin_amdgcn_mfma_f32_16x16x32_bf16(a, bh, accH[n], 0, 0, 0);
            accT[n] = __builtin_amdgcn_mfma_f32_16x16x32_bf16(a, bt, accT[n], 0, 0, 0);
        }
    }
    #pragma unroll
    for (int n = 0; n < 8; ++n){
        int cc = n*16 + lr;
        #pragma unroll
        for (int j = 0; j < 4; ++j){
            int mr = m0 + wv*16 + lg*4 + j;
            if (mr < N){
                H[(size_t)mr*CH + cc] = f2bf(accH[n][j]);
                T[(size_t)mr*CH + cc] = f2bf(accT[n][j]);
            }
        }
    }
}

// ---------------------------------------------------------------------------
// k2v (R13 winner, verbatim): u=h+t pre-add into dead B region, frag-linear
//   VB4 store from registers, manual RNE packing (R15's asm cvt_pk reverted).
// ---------------------------------------------------------------------------
__global__ __launch_bounds__(512, 2) void k2v(
        const float* __restrict__ ea, const int* __restrict__ eidx,
        const unsigned short* __restrict__ wT,
        const unsigned short* __restrict__ Hm, const unsigned short* __restrict__ Tm,
        uint4* __restrict__ VB4, float* __restrict__ sums, int E){
    __shared__ __align__(16) unsigned char smem[66560];   // A 32K | B->U 32K | red 1K
    float* red = (float*)(smem + 65536);
    const int tid = threadIdx.x;
    const int e0 = blockIdx.x * 128;
    if (tid < 256) red[tid] = 0.f;

    // ---- phase 0: edge-index loads ----
    int ri4[4], ci4[4];
    #pragma unroll
    for (int i = 0; i < 4; ++i){
        int r = (tid + i*512) >> 4;
        ri4[i] = eidx[e0 + r];
        ci4[i] = eidx[E + e0 + r];
    }
    __builtin_amdgcn_sched_barrier(0);
    // ---- phase 1: weight tile loads (L2-hot) ----
    uint4 wv4[4];
    #pragma unroll
    for (int i = 0; i < 4; ++i){
        int g = tid + i*512;
        int n = g >> 4, k8 = (g & 15)*8;
        wv4[i] = *(const uint4*)(wT + n*CH + k8);
    }
    __builtin_amdgcn_sched_barrier(0);
    // ---- phase 2: streaming ea loads ----
    float4 eav[8];
    #pragma unroll
    for (int i = 0; i < 8; ++i){
        int g = tid + i*512;
        int row = g >> 5, col4 = (g & 31)*4;
        eav[i] = *(const float4*)(ea + (size_t)(e0+row)*CH + col4);
    }
    __builtin_amdgcn_sched_barrier(0);
    // ---- phase 3: issue H/T gathers (vmcnt waits only eidx) ----
    uint4 hv[4], tv[4];
    #pragma unroll
    for (int i = 0; i < 4; ++i){
        int c = (tid + i*512) & 15;
        hv[i] = *(const uint4*)(Hm + (size_t)ri4[i]*CH + c*8);
        tv[i] = *(const uint4*)(Tm + (size_t)ci4[i]*CH + c*8);
    }
    __builtin_amdgcn_sched_barrier(0);
    // ---- phase 4: wv4 -> B LDS (wv4 dies; eav+gathers stay in flight) ----
    #pragma unroll
    for (int i = 0; i < 4; ++i){
        int g = tid + i*512;
        int n = g >> 4, k8 = (g & 15)*8;
        unsigned int b = ((unsigned int)(n*256 + k8*2)) ^ ((unsigned int)(n & 7) << 4);
        *(uint4*)(smem + 32768 + b) = wv4[i];
    }
    __builtin_amdgcn_sched_barrier(0);
    // ---- phase 5: stage ea -> bf16 A LDS (gathers stay out) ----
    #pragma unroll
    for (int i = 0; i < 8; ++i){
        int g = tid + i*512;
        int row = g >> 5, col4 = (g & 31)*4;
        float4 v = eav[i];
        unsigned int lo = (unsigned int)f2bf(v.x) | ((unsigned int)f2bf(v.y) << 16);
        unsigned int hi = (unsigned int)f2bf(v.z) | ((unsigned int)f2bf(v.w) << 16);
        unsigned int b = ((unsigned int)(row*256 + col4*2)) ^ ((unsigned int)(row & 7) << 4);
        *(uint2*)(smem + b) = make_uint2(lo, hi);
    }
    // B1: LDS-only barrier (gathers NOT drained)
    asm volatile("s_waitcnt lgkmcnt(0)\n\ts_barrier" ::: "memory");

    const int lane = tid & 63, wv = tid >> 6;
    const int lr = lane & 15, lg = lane >> 4;
    f32x4 acc[8];
    #pragma unroll
    for (int n = 0; n < 8; ++n) acc[n] = (f32x4){0.f,0.f,0.f,0.f};
    #pragma unroll
    for (int kk = 0; kk < 4; ++kk){
        int arow = wv*16 + lr;
        unsigned int ab = ((unsigned int)(arow*256 + kk*64 + lg*16)) ^ ((unsigned int)(arow & 7) << 4);
        bf16x8 a = *(const bf16x8*)(smem + ab);
        #pragma unroll
        for (int n = 0; n < 8; ++n){
            int cc = n*16 + lr;
            unsigned int bb = ((unsigned int)(cc*256 + kk*64 + lg*16)) ^ ((unsigned int)(cc & 7) << 4);
            bf16x8 bw = *(const bf16x8*)(smem + 32768 + bb);
            acc[n] = __builtin_amdgcn_mfma_f32_16x16x32_bf16(a, bw, acc[n], 0, 0, 0);
        }
    }
    // ---- residual: read staged ea (bf16) ----
    float res[32];
    #pragma unroll
    for (int n = 0; n < 8; ++n){
        int cc = n*16 + lr;
        #pragma unroll
        for (int j = 0; j < 4; ++j){
            int ml = wv*16 + lg*4 + j;
            unsigned int b = ((unsigned int)(ml*256 + cc*2)) ^ ((unsigned int)(ml & 7) << 4);
            res[n*4 + j] = bf2f(*(const unsigned short*)(smem + b));
        }
    }
    asm volatile("s_waitcnt lgkmcnt(0)\n\ts_barrier" ::: "memory");   // B2: B region free
    // ---- redistribute: u = h+t -> u-tile (B region), 4 b128 writes ----
    #pragma unroll
    for (int i = 0; i < 4; ++i){
        int g = tid + i*512;
        int r = g >> 4, c = g & 15;
        uint4 u4;
        u4.x = pairadd_bf(hv[i].x, tv[i].x);
        u4.y = pairadd_bf(hv[i].y, tv[i].y);
        u4.z = pairadd_bf(hv[i].z, tv[i].z);
        u4.w = pairadd_bf(hv[i].w, tv[i].w);
        unsigned int b = ((unsigned int)(r*256 + c*16)) ^ ((unsigned int)((r >> 2) & 3) << 5);
        *(uint4*)(smem + 32768 + b) = u4;
    }
    asm volatile("s_waitcnt lgkmcnt(0)\n\ts_barrier" ::: "memory");   // B3: u visible
    // ---- epilogue: v = o0*(1+0.5u) + res; stats; frag-linear VB4 store ----
    #pragma unroll
    for (int n2 = 0; n2 < 4; ++n2){
        unsigned int ow[4];
        #pragma unroll
        for (int h = 0; h < 2; ++h){
            int nn = n2*2 + h;
            int cc = nn*16 + lr;
            float s = 0.f, ss = 0.f;
            unsigned int w0 = 0, w1 = 0;
            #pragma unroll
            for (int j = 0; j < 4; ++j){
                int ml = wv*16 + lg*4 + j;
                unsigned int b = ((unsigned int)(ml*256 + cc*2)) ^ ((unsigned int)((ml >> 2) & 3) << 5);
                float u = bf2f(*(const unsigned short*)(smem + 32768 + b));
                float o0 = acc[nn][j];
                float v = fmaf(o0, 0.5f*u, o0) + res[nn*4 + j];
                s += v; ss += v*v;
                unsigned int bv = (unsigned int)f2bf(v);
                if (j < 2) w0 |= bv << (j*16);
                else       w1 |= bv << ((j-2)*16);
            }
            ow[h*2] = w0; ow[h*2+1] = w1;
            s  += __shfl_xor(s, 16);  s  += __shfl_xor(s, 32);
            ss += __shfl_xor(ss, 16); ss += __shfl_xor(ss, 32);
            if (lane < 16){
                atomicAdd(&red[cc], s);
                atomicAdd(&red[CH + cc], ss);
            }
        }
        uint4 o; o.x = ow[0]; o.y = ow[1]; o.z = ow[2]; o.w = ow[3];
        VB4[((size_t)(blockIdx.x*8 + wv)*4 + n2)*64 + lane] = o;   // coalesced 1KB/wave
    }
    asm volatile("s_waitcnt lgkmcnt(0)\n\ts_barrier" ::: "memory");   // red complete
    if (tid < 256) atomicAdd(&sums[(blockIdx.x & 255)*256 + tid], red[tid]);
}

// ---------------------------------------------------------------------------
// k3: reduce 256 slots -> per-channel scale/shift (sb)
// ---------------------------------------------------------------------------
__global__ __launch_bounds__(128) void k3_stats(
        const float* __restrict__ sums, const float* __restrict__ gamma,
        const float* __restrict__ beta, float* __restrict__ sb, float invE){
    int c = threadIdx.x;
    float s = 0.f, ss = 0.f;
    for (int i = 0; i < 256; ++i){ s += sums[i*256 + c]; ss += sums[i*256 + CH + c]; }
    float mean = s * invE;
    float var = ss * invE - mean*mean;     // biased variance (matches reference)
    float inv = rsqrtf(var + 1e-5f);
    float sc = gamma[c] * inv;
    sb[c] = sc;
    sb[CH + c] = beta[c] - mean * sc;
}

// ---------------------------------------------------------------------------
// kE1 v4: decode fragment-linear VB4, BN+ReLU, 64B-segment f32 stores.
//   stride (grid*256) is a multiple of 2048 -> lane/n2/wv and the per-thread
//   scale/shift are LOOP-INVARIANT: hoisted. 2 independent uint4s per trip
//   (2x MLP), grid 4096.
// ---------------------------------------------------------------------------
__global__ __launch_bounds__(256) void kE1(
        const uint4* __restrict__ VB4, const float* __restrict__ sb,
        float* __restrict__ out, int nt){
    const int i0 = blockIdx.x * 256 + threadIdx.x;
    const int stride = gridDim.x * 256;           // 4096*256 = 2^20 (mult of 2048)
    const int lane = i0 & 63, n2 = (i0 >> 6) & 3, wv = (i0 >> 8) & 7;
    const int lr = lane & 15, lg = lane >> 4;
    const int colA = n2*32 + lr, colB = colA + 16;
    const float scA = sb[colA], shA = sb[CH + colA];
    const float scB = sb[colB], shB = sb[CH + colB];
    const int rowoff = wv*16 + lg*4;
    for (int i = i0; i < nt; i += 2*stride){
        int j = i + stride;
        bool ok2 = (j < nt);
        uint4 v1 = VB4[i];
        uint4 v2;
        if (ok2) v2 = VB4[j];
        {
            float* o = out + ((size_t)(i >> 11)*128 + rowoff)*CH;
            o[0*CH + colA] = fmaxf(fmaf(bf2f((unsigned short)(v1.x & 0xffff)), scA, shA), 0.f);
            o[1*CH + colA] = fmaxf(fmaf(bf2f((unsigned short)(v1.x >> 16)),    scA, shA), 0.f);
            o[2*CH + colA] = fmaxf(fmaf(bf2f((unsigned short)(v1.y & 0xffff)), scA, shA), 0.f);
            o[3*CH + colA] = fmaxf(fmaf(bf2f((unsigned short)(v1.y >> 16)),    scA, shA), 0.f);
            o[0*CH + colB] = fmaxf(fmaf(bf2f((unsigned short)(v1.z & 0xffff)), scB, shB), 0.f);
            o[1*CH + colB] = fmaxf(fmaf(bf2f((unsigned short)(v1.z >> 16)),    scB, shB), 0.f);
            o[2*CH + colB] = fmaxf(fmaf(bf2f((unsigned short)(v1.w & 0xffff)), scB, shB), 0.f);
            o[3*CH + colB] = fmaxf(fmaf(bf2f((unsigned short)(v1.w >> 16)),    scB, shB), 0.f);
        }
        if (ok2){
            float* o = out + ((size_t)(j >> 11)*128 + rowoff)*CH;
            o[0*CH + colA] = fmaxf(fmaf(bf2f((unsigned short)(v2.x & 0xffff)), scA, shA), 0.f);
            o[1*CH + colA] = fmaxf(fmaf(bf2f((unsigned short)(v2.x >> 16)),    scA, shA), 0.f);
            o[2*CH + colA] = fmaxf(fmaf(bf2f((unsigned short)(v2.y & 0xffff)), scA, shA), 0.f);
            o[3*CH + colA] = fmaxf(fmaf(bf2f((unsigned short)(v2.y >> 16)),    scA, shA), 0.f);
            o[0*CH + colB] = fmaxf(fmaf(bf2f((unsigned short)(v2.z & 0xffff)), scB, shB), 0.f);
            o[1*CH + colB] = fmaxf(fmaf(bf2f((unsigned short)(v2.z >> 16)),    scB, shB), 0.f);
            o[2*CH + colB] = fmaxf(fmaf(bf2f((unsigned short)(v2.w & 0xffff)), scB, shB), 0.f);
            o[3*CH + colB] = fmaxf(fmaf(bf2f((unsigned short)(v2.w >> 16)),    scB, shB), 0.f);
        }
    }
}

extern "C" void kernel_launch(void* const* d_in, const int* in_sizes, int n_in,
                              void* d_out, int out_size, void* d_ws, size_t ws_size,
                              hipStream_t stream) {
    const float* x      = (const float*)d_in[0];
    const int*   eidx   = (const int*)d_in[1];
    const float* ea     = (const float*)d_in[2];
    const float* w_self = (const float*)d_in[4];
    const float* w_h    = (const float*)d_in[5];
    const float* w_t    = (const float*)d_in[6];
    const float* gamma  = (const float*)d_in[7];
    const float* beta   = (const float*)d_in[8];
    float* out = (float*)d_out;

    const int N = in_sizes[0] / CH;     // 40000
    const int E = in_sizes[3];          // 640000

    // workspace carve-up (~185 MB total — proven to fit since R5):
    float* sums = (float*)d_ws;                          // 256*256 f32
    float* sb   = sums + 256*256;                        // 256 f32
    unsigned short* wT = (unsigned short*)(sb + 256);    // 3*128*128 bf16
    unsigned short* H  = wT + 3*CH*CH;                   // N*128 bf16
    unsigned short* T  = H + (size_t)N*CH;               // N*128 bf16
    uint4* VB4 = (uint4*)(T + (size_t)N*CH);             // E*128 bf16 (frag-linear)

    k0_prep<<<256, 256, 0, stream>>>(w_self, w_h, w_t, wT, sums);
    k1_ht  <<<(N + 127)/128, 512, 0, stream>>>(x, wT, H, T, N);
    k2v    <<<E/128, 512, 0, stream>>>(ea, eidx, wT, H, T, VB4, sums, E);
    k3_stats<<<1, 128, 0, stream>>>(sums, gamma, beta, sb, 1.0f/(float)E);
    kE1    <<<4096, 256, 0, stream>>>(VB4, sb, out, E*CH/8);
}